// Round 6
// baseline (452.788 us; speedup 1.0000x reference)
//
#include <hip/hip_runtime.h>
#include <hip/hip_bf16.h>

#define N_SITES 100000
#define C_IN 256
#define C_MID 64
#define C_OUT 256

typedef __attribute__((ext_vector_type(8))) short bf16x8;   // 8 bf16 in 4 VGPRs
typedef __attribute__((ext_vector_type(4))) float f32x4;    // MFMA C/D frag

__device__ inline short f2bf(float f) {
  // native cast: compiler fuses adjacent pairs into v_cvt_pk_bf16_f32
  return __builtin_bit_cast(short, __float2bfloat16(f));
}

__device__ inline f32x4 mfma16(bf16x8 a, bf16x8 b, f32x4 c) {
  return __builtin_amdgcn_mfma_f32_16x16x32_bf16(a, b, c, 0, 0, 0);
}

// ---------------------------------------------------------------------------
// Prep: W1T[n][k] = W1[k][n] (bf16), W2T[k][dout][din] = W2[k][din][dout],
//       W3T[n][k] = W3[k][n], zero h1 pad row (row N_SITES).
// ---------------------------------------------------------------------------
__global__ __launch_bounds__(256) void k_prep(const float* __restrict__ W1,
                                              const float* __restrict__ W2,
                                              const float* __restrict__ W3,
                                              short* __restrict__ W1T,
                                              short* __restrict__ W2T,
                                              short* __restrict__ W3T,
                                              short* __restrict__ h1) {
  int i = blockIdx.x * 256 + threadIdx.x;
  if (i < 16384) {                       // W1T: [64][256]
    int n = i >> 8, k = i & 255;
    W1T[i] = f2bf(W1[k * 64 + n]);
  } else if (i < 16384 + 110592) {       // W2T: [27][64][64]
    int j = i - 16384;
    int k = j >> 12, rem = j & 4095;
    int dout = rem >> 6, din = rem & 63;
    W2T[j] = f2bf(W2[k * 4096 + din * 64 + dout]);
  } else if (i < 16384 + 110592 + 16384) {  // W3T: [256][64]
    int j = i - (16384 + 110592);
    int n = j >> 6, k = j & 63;
    W3T[j] = f2bf(W3[k * 256 + n]);
  } else if (i < 16384 + 110592 + 16384 + 64) {  // h1 pad row
    h1[(size_t)N_SITES * 64 + (i - (16384 + 110592 + 16384))] = 0;
  }
}

// ---------------------------------------------------------------------------
// conv1: h1[n][c] = relu(g1[c] * (F @ W1)[n][c] + b1[c]), bf16 out.
// 4 waves/block, 16 rows/wave. All 16 F-loads hoisted (16 outstanding vmem).
// ---------------------------------------------------------------------------
__global__ __launch_bounds__(256, 4) void k_conv1(const float* __restrict__ F,
                                                  const short* __restrict__ W1T,
                                                  const float* __restrict__ g1,
                                                  const float* __restrict__ b1,
                                                  short* __restrict__ h1) {
  int tid = threadIdx.x;
  int lane = tid & 63, wave = tid >> 6;
  int l15 = lane & 15, l4 = lane >> 4;
  int base = blockIdx.x * 64 + wave * 16;

  int row = base + l15;
  int rowc = row < N_SITES ? row : (N_SITES - 1);
  const float* fr = F + (size_t)rowc * 256 + l4 * 8;

  float4 fa[16];
#pragma unroll
  for (int kk = 0; kk < 8; ++kk) {
    fa[2 * kk]     = *(const float4*)(fr + kk * 32);
    fa[2 * kk + 1] = *(const float4*)(fr + kk * 32 + 4);
  }

  f32x4 acc[4];
#pragma unroll
  for (int nf = 0; nf < 4; ++nf) acc[nf] = (f32x4){0.f, 0.f, 0.f, 0.f};

#pragma unroll
  for (int kk = 0; kk < 8; ++kk) {
    float4 a0 = fa[2 * kk], a1 = fa[2 * kk + 1];
    bf16x8 af;
    af[0] = f2bf(a0.x); af[1] = f2bf(a0.y); af[2] = f2bf(a0.z); af[3] = f2bf(a0.w);
    af[4] = f2bf(a1.x); af[5] = f2bf(a1.y); af[6] = f2bf(a1.z); af[7] = f2bf(a1.w);
#pragma unroll
    for (int nf = 0; nf < 4; ++nf) {
      bf16x8 bf = *(const bf16x8*)(W1T + (nf * 16 + l15) * 256 + kk * 32 + l4 * 8);
      acc[nf] = mfma16(af, bf, acc[nf]);
    }
  }

#pragma unroll
  for (int nf = 0; nf < 4; ++nf) {
    int col = nf * 16 + l15;
    float g = g1[col], bb = b1[col];
#pragma unroll
    for (int r = 0; r < 4; ++r) {
      int site = base + l4 * 4 + r;   // D row = (lane>>4)*4 + reg
      if (site < N_SITES) {
        float v = fmaxf(acc[nf][r] * g + bb, 0.f);
        h1[(size_t)site * 64 + col] = f2bf(v);
      }
    }
  }
}

// ---------------------------------------------------------------------------
// conv2: gather-GEMM over 27 neighbors, 16 rows/wave (64/block) for occupancy,
// depth-1 software prefetch of gathered A-frags.
// ---------------------------------------------------------------------------
__global__ __launch_bounds__(256, 6) void k_conv2(const short* __restrict__ h1,
                                                  const short* __restrict__ W2T,
                                                  const float* __restrict__ g2,
                                                  const float* __restrict__ b2,
                                                  const int* __restrict__ NB,
                                                  short* __restrict__ h2) {
  __shared__ int nbt[64 * 27];
  int tid = threadIdx.x;
  int blockbase = blockIdx.x * 64;
  for (int i = tid; i < 64 * 27; i += 256) {
    int site = blockbase + i / 27;
    nbt[i] = (site < N_SITES) ? NB[(size_t)site * 27 + (i % 27)] : N_SITES;
  }
  __syncthreads();

  int lane = tid & 63, wave = tid >> 6;
  int l15 = lane & 15, l4 = lane >> 4;
  const int* myNb = nbt + (wave * 16 + l15) * 27;
  const short* wbase = W2T + l15 * 64 + l4 * 8;

  f32x4 acc[4];
#pragma unroll
  for (int nf = 0; nf < 4; ++nf) acc[nf] = (f32x4){0.f, 0.f, 0.f, 0.f};

  // prefetch k=0
  int n0 = myNb[0];
  const short* p = h1 + (size_t)n0 * 64 + l4 * 8;
  bf16x8 a0 = *(const bf16x8*)p;
  bf16x8 a1 = *(const bf16x8*)(p + 32);

  for (int k = 0; k < 27; ++k) {
    // prefetch next neighbor's A-frags (clamped on the tail; dead values there)
    int kn = k < 26 ? k + 1 : 26;
    int n = myNb[kn];
    const short* q = h1 + (size_t)n * 64 + l4 * 8;
    bf16x8 na0 = *(const bf16x8*)q;
    bf16x8 na1 = *(const bf16x8*)(q + 32);

    const short* wk = wbase + k * 4096;
#pragma unroll
    for (int nf = 0; nf < 4; ++nf) {
      bf16x8 b0 = *(const bf16x8*)(wk + nf * 1024);
      bf16x8 b1 = *(const bf16x8*)(wk + nf * 1024 + 32);
      acc[nf] = mfma16(a0, b0, acc[nf]);
      acc[nf] = mfma16(a1, b1, acc[nf]);
    }
    a0 = na0;
    a1 = na1;
  }

#pragma unroll
  for (int nf = 0; nf < 4; ++nf) {
    int col = nf * 16 + l15;
    float g = g2[col], bb = b2[col];
#pragma unroll
    for (int r = 0; r < 4; ++r) {
      int site = blockbase + wave * 16 + l4 * 4 + r;
      if (site < N_SITES) {
        float v = fmaxf(acc[nf][r] * g + bb, 0.f);
        h2[(size_t)site * 64 + col] = f2bf(v);
      }
    }
  }
}

// ---------------------------------------------------------------------------
// conv3 + affine + residual + relu, fp32 out. SWAPPED operands:
// A = W3T (rows = out-channels), B = h2 (rows = sites) -> D[chan][site].
// Lane holds 4 CONSECUTIVE channels of one site -> float4 residual+store.
// 4 waves/block, 16 sites/wave.
// ---------------------------------------------------------------------------
__global__ __launch_bounds__(256, 4) void k_conv3(const short* __restrict__ h2,
                                                  const short* __restrict__ W3T,
                                                  const float* __restrict__ g3,
                                                  const float* __restrict__ b3,
                                                  const float* __restrict__ F,
                                                  float* __restrict__ out) {
  int tid = threadIdx.x;
  int lane = tid & 63, wave = tid >> 6;
  int l15 = lane & 15, l4 = lane >> 4;
  int sbase = blockIdx.x * 64 + wave * 16;

  int site = sbase + l15;
  int sitec = site < N_SITES ? site : (N_SITES - 1);
  const short* pb = h2 + (size_t)sitec * 64 + l4 * 8;
  bf16x8 bv0 = *(const bf16x8*)pb;
  bf16x8 bv1 = *(const bf16x8*)(pb + 32);

  f32x4 acc[16];
#pragma unroll
  for (int nb = 0; nb < 16; ++nb) acc[nb] = (f32x4){0.f, 0.f, 0.f, 0.f};

#pragma unroll
  for (int nb = 0; nb < 16; ++nb) {
    const short* pa = W3T + (nb * 16 + l15) * 64 + l4 * 8;
    bf16x8 a0 = *(const bf16x8*)pa;
    bf16x8 a1 = *(const bf16x8*)(pa + 32);
    acc[nb] = mfma16(a0, bv0, acc[nb]);
    acc[nb] = mfma16(a1, bv1, acc[nb]);
  }

  // D row = chan (within 16-block): l4*4 + r ; D col = site: l15
  if (site < N_SITES) {
#pragma unroll
    for (int nb = 0; nb < 16; ++nb) {
      int chan = nb * 16 + l4 * 4;
      size_t o = (size_t)site * 256 + chan;
      float4 g = *(const float4*)(g3 + chan);
      float4 bb = *(const float4*)(b3 + chan);
      float4 fv = *(const float4*)(F + o);
      float4 r;
      r.x = fmaxf(acc[nb][0] * g.x + bb.x + fv.x, 0.f);
      r.y = fmaxf(acc[nb][1] * g.y + bb.y + fv.y, 0.f);
      r.z = fmaxf(acc[nb][2] * g.z + bb.z + fv.z, 0.f);
      r.w = fmaxf(acc[nb][3] * g.w + bb.w + fv.w, 0.f);
      *(float4*)(out + o) = r;
    }
  }
}

// ---------------------------------------------------------------------------
extern "C" void kernel_launch(void* const* d_in, const int* in_sizes, int n_in,
                              void* d_out, int out_size, void* d_ws, size_t ws_size,
                              hipStream_t stream) {
  const float* F  = (const float*)d_in[0];
  const float* W1 = (const float*)d_in[1];
  const float* W2 = (const float*)d_in[2];
  const float* W3 = (const float*)d_in[3];
  const float* g1 = (const float*)d_in[4];
  const float* b1 = (const float*)d_in[5];
  const float* g2 = (const float*)d_in[6];
  const float* b2 = (const float*)d_in[7];
  const float* g3 = (const float*)d_in[8];
  const float* b3 = (const float*)d_in[9];
  const int*   NB = (const int*)d_in[10];
  float* out = (float*)d_out;

  char* ws = (char*)d_ws;
  short* W1T = (short*)(ws);                                   // 32768 B
  short* W2T = (short*)(ws + 32768);                           // 221184 B
  short* W3T = (short*)(ws + 32768 + 221184);                  // 32768 B
  short* h1  = (short*)(ws + 32768 + 221184 + 32768);          // (N+1)*64*2 = 12800128 B
  short* h2  = (short*)(ws + 32768 + 221184 + 32768 + 12800128); // N*64*2 B

  k_prep<<<dim3(561), dim3(256), 0, stream>>>(W1, W2, W3, W1T, W2T, W3T, h1);
  k_conv1<<<dim3((N_SITES + 63) / 64), dim3(256), 0, stream>>>(F, W1T, g1, b1, h1);
  k_conv2<<<dim3((N_SITES + 63) / 64), dim3(256), 0, stream>>>(h1, W2T, g2, b2, NB, h2);
  k_conv3<<<dim3((N_SITES + 63) / 64), dim3(256), 0, stream>>>(h2, W3T, g3, b3, F, out);
}

// Round 7
// 349.292 us; speedup vs baseline: 1.2963x; 1.2963x over previous
//
#include <hip/hip_runtime.h>
#include <hip/hip_bf16.h>

#define N_SITES 100000
#define C_IN 256
#define C_MID 64
#define C_OUT 256

typedef __attribute__((ext_vector_type(8))) short bf16x8;   // 8 bf16 in 4 VGPRs
typedef __attribute__((ext_vector_type(4))) float f32x4;    // MFMA C/D frag

__device__ inline short f2bf(float f) {
  // native cast: compiler fuses adjacent pairs into v_cvt_pk_bf16_f32
  return __builtin_bit_cast(short, __float2bfloat16(f));
}

__device__ inline f32x4 mfma16(bf16x8 a, bf16x8 b, f32x4 c) {
  return __builtin_amdgcn_mfma_f32_16x16x32_bf16(a, b, c, 0, 0, 0);
}

// ---------------------------------------------------------------------------
// Prep: W1T[n][k] = W1[k][n] (bf16), W2T[k][dout][din] = W2[k][din][dout],
//       W3T[n][k] = W3[k][n], zero h1 pad row (row N_SITES).
// ---------------------------------------------------------------------------
__global__ __launch_bounds__(256) void k_prep(const float* __restrict__ W1,
                                              const float* __restrict__ W2,
                                              const float* __restrict__ W3,
                                              short* __restrict__ W1T,
                                              short* __restrict__ W2T,
                                              short* __restrict__ W3T,
                                              short* __restrict__ h1) {
  int i = blockIdx.x * 256 + threadIdx.x;
  if (i < 16384) {                       // W1T: [64][256]
    int n = i >> 8, k = i & 255;
    W1T[i] = f2bf(W1[k * 64 + n]);
  } else if (i < 16384 + 110592) {       // W2T: [27][64][64]
    int j = i - 16384;
    int k = j >> 12, rem = j & 4095;
    int dout = rem >> 6, din = rem & 63;
    W2T[j] = f2bf(W2[k * 4096 + din * 64 + dout]);
  } else if (i < 16384 + 110592 + 16384) {  // W3T: [256][64]
    int j = i - (16384 + 110592);
    int n = j >> 6, k = j & 63;
    W3T[j] = f2bf(W3[k * 256 + n]);
  } else if (i < 16384 + 110592 + 16384 + 64) {  // h1 pad row
    h1[(size_t)N_SITES * 64 + (i - (16384 + 110592 + 16384))] = 0;
  }
}

// ---------------------------------------------------------------------------
// conv1: h1[n][c] = relu(g1[c] * (F @ W1)[n][c] + b1[c]), bf16 out.
// 4 waves/block, 16 rows/wave. All 16 F-loads hoisted (16 outstanding vmem).
// ---------------------------------------------------------------------------
__global__ __launch_bounds__(256, 4) void k_conv1(const float* __restrict__ F,
                                                  const short* __restrict__ W1T,
                                                  const float* __restrict__ g1,
                                                  const float* __restrict__ b1,
                                                  short* __restrict__ h1) {
  int tid = threadIdx.x;
  int lane = tid & 63, wave = tid >> 6;
  int l15 = lane & 15, l4 = lane >> 4;
  int base = blockIdx.x * 64 + wave * 16;

  int row = base + l15;
  int rowc = row < N_SITES ? row : (N_SITES - 1);
  const float* fr = F + (size_t)rowc * 256 + l4 * 8;

  float4 fa[16];
#pragma unroll
  for (int kk = 0; kk < 8; ++kk) {
    fa[2 * kk]     = *(const float4*)(fr + kk * 32);
    fa[2 * kk + 1] = *(const float4*)(fr + kk * 32 + 4);
  }

  f32x4 acc[4];
#pragma unroll
  for (int nf = 0; nf < 4; ++nf) acc[nf] = (f32x4){0.f, 0.f, 0.f, 0.f};

#pragma unroll
  for (int kk = 0; kk < 8; ++kk) {
    float4 a0 = fa[2 * kk], a1 = fa[2 * kk + 1];
    bf16x8 af;
    af[0] = f2bf(a0.x); af[1] = f2bf(a0.y); af[2] = f2bf(a0.z); af[3] = f2bf(a0.w);
    af[4] = f2bf(a1.x); af[5] = f2bf(a1.y); af[6] = f2bf(a1.z); af[7] = f2bf(a1.w);
#pragma unroll
    for (int nf = 0; nf < 4; ++nf) {
      bf16x8 bf = *(const bf16x8*)(W1T + (nf * 16 + l15) * 256 + kk * 32 + l4 * 8);
      acc[nf] = mfma16(af, bf, acc[nf]);
    }
  }

#pragma unroll
  for (int nf = 0; nf < 4; ++nf) {
    int col = nf * 16 + l15;
    float g = g1[col], bb = b1[col];
#pragma unroll
    for (int r = 0; r < 4; ++r) {
      int site = base + l4 * 4 + r;   // D row = (lane>>4)*4 + reg
      if (site < N_SITES) {
        float v = fmaxf(acc[nf][r] * g + bb, 0.f);
        h1[(size_t)site * 64 + col] = f2bf(v);
      }
    }
  }
}

// ---------------------------------------------------------------------------
// conv2: gather-GEMM over 27 neighbors. B-reload-traffic bound -> amortize:
// 64 rows/wave (B-traffic = 100000/64 waves * 27 * 8KB = 338 MB), 2 waves/
// block (128 rows), ping-pong depth-1 gather prefetch, no VGPR cap,
// XCD-chunked bijective block swizzle for h1 L2 locality.
// ---------------------------------------------------------------------------
__global__ __launch_bounds__(128) void k_conv2(const short* __restrict__ h1,
                                               const short* __restrict__ W2T,
                                               const float* __restrict__ g2,
                                               const float* __restrict__ b2,
                                               const int* __restrict__ NB,
                                               short* __restrict__ h2) {
  __shared__ int nbt[128 * 27];
  int tid = threadIdx.x;

  // XCD-chunked bijective swizzle (m204 formula): contiguous chunks per XCD
  int nwg = gridDim.x;
  int q = nwg >> 3, r = nwg & 7;
  int xcd = blockIdx.x & 7, idx = blockIdx.x >> 3;
  int swz = (xcd < r) ? (xcd * (q + 1) + idx)
                      : (r * (q + 1) + (xcd - r) * q + idx);
  int blockbase = swz * 128;

  for (int i = tid; i < 128 * 27; i += 128) {
    int site = blockbase + i / 27;
    nbt[i] = (site < N_SITES) ? NB[(size_t)site * 27 + (i % 27)] : N_SITES;
  }
  __syncthreads();

  int lane = tid & 63, wave = tid >> 6;
  int l15 = lane & 15, l4 = lane >> 4;
  int wrow = wave * 64 + l15;   // lane's base row within block; +mf*16

  f32x4 acc[4][4];              // [mf][nf]
#pragma unroll
  for (int mf = 0; mf < 4; ++mf)
#pragma unroll
    for (int nf = 0; nf < 4; ++nf) acc[mf][nf] = (f32x4){0.f, 0.f, 0.f, 0.f};

  bf16x8 bufA[4][2], bufB[4][2];

#define LOADBUF(BUF, KK)                                                    \
  {                                                                         \
    _Pragma("unroll")                                                       \
    for (int mf = 0; mf < 4; ++mf) {                                        \
      int n = nbt[(wrow + mf * 16) * 27 + (KK)];                            \
      const short* p = h1 + (size_t)n * 64 + l4 * 8;                        \
      BUF[mf][0] = *(const bf16x8*)p;                                       \
      BUF[mf][1] = *(const bf16x8*)(p + 32);                                \
    }                                                                       \
  }

#define COMPUTE(BUF, KK)                                                    \
  {                                                                         \
    const short* wk = W2T + (size_t)(KK) * 4096 + l15 * 64 + l4 * 8;        \
    _Pragma("unroll")                                                       \
    for (int nf = 0; nf < 4; ++nf) {                                        \
      bf16x8 b0 = *(const bf16x8*)(wk + nf * 1024);                         \
      bf16x8 b1 = *(const bf16x8*)(wk + nf * 1024 + 32);                    \
      _Pragma("unroll")                                                     \
      for (int mf = 0; mf < 4; ++mf) {                                      \
        acc[mf][nf] = mfma16(BUF[mf][0], b0, acc[mf][nf]);                  \
        acc[mf][nf] = mfma16(BUF[mf][1], b1, acc[mf][nf]);                  \
      }                                                                     \
    }                                                                       \
  }

  LOADBUF(bufA, 0);
  for (int k = 0; k < 26; k += 2) {
    LOADBUF(bufB, k + 1);                       // prefetch k+1
    COMPUTE(bufA, k);                           // compute k
    LOADBUF(bufA, (k + 2 < 27) ? k + 2 : 26);   // prefetch k+2 (clamped)
    COMPUTE(bufB, k + 1);                       // compute k+1
  }
  COMPUTE(bufA, 26);                            // tail (27 is odd)

#undef LOADBUF
#undef COMPUTE

#pragma unroll
  for (int mf = 0; mf < 4; ++mf) {
#pragma unroll
    for (int nf = 0; nf < 4; ++nf) {
      int col = nf * 16 + l15;
      float g = g2[col], bb = b2[col];
#pragma unroll
      for (int rr = 0; rr < 4; ++rr) {
        int site = blockbase + wave * 64 + mf * 16 + l4 * 4 + rr;
        if (site < N_SITES) {
          float v = fmaxf(acc[mf][nf][rr] * g + bb, 0.f);
          h2[(size_t)site * 64 + col] = f2bf(v);
        }
      }
    }
  }
}

// ---------------------------------------------------------------------------
// conv3 + affine + residual + relu, fp32 out. SWAPPED operands:
// A = W3T (rows = out-channels), B = h2 (rows = sites) -> D[chan][site].
// Lane holds 4 CONSECUTIVE channels of one site -> float4 residual+store.
// 4 waves/block, 16 sites/wave.
// ---------------------------------------------------------------------------
__global__ __launch_bounds__(256, 4) void k_conv3(const short* __restrict__ h2,
                                                  const short* __restrict__ W3T,
                                                  const float* __restrict__ g3,
                                                  const float* __restrict__ b3,
                                                  const float* __restrict__ F,
                                                  float* __restrict__ out) {
  int tid = threadIdx.x;
  int lane = tid & 63, wave = tid >> 6;
  int l15 = lane & 15, l4 = lane >> 4;
  int sbase = blockIdx.x * 64 + wave * 16;

  int site = sbase + l15;
  int sitec = site < N_SITES ? site : (N_SITES - 1);
  const short* pb = h2 + (size_t)sitec * 64 + l4 * 8;
  bf16x8 bv0 = *(const bf16x8*)pb;
  bf16x8 bv1 = *(const bf16x8*)(pb + 32);

  f32x4 acc[16];
#pragma unroll
  for (int nb = 0; nb < 16; ++nb) acc[nb] = (f32x4){0.f, 0.f, 0.f, 0.f};

#pragma unroll
  for (int nb = 0; nb < 16; ++nb) {
    const short* pa = W3T + (nb * 16 + l15) * 64 + l4 * 8;
    bf16x8 a0 = *(const bf16x8*)pa;
    bf16x8 a1 = *(const bf16x8*)(pa + 32);
    acc[nb] = mfma16(a0, bv0, acc[nb]);
    acc[nb] = mfma16(a1, bv1, acc[nb]);
  }

  // D row = chan (within 16-block): l4*4 + r ; D col = site: l15
  if (site < N_SITES) {
#pragma unroll
    for (int nb = 0; nb < 16; ++nb) {
      int chan = nb * 16 + l4 * 4;
      size_t o = (size_t)site * 256 + chan;
      float4 g = *(const float4*)(g3 + chan);
      float4 bb = *(const float4*)(b3 + chan);
      float4 fv = *(const float4*)(F + o);
      float4 r;
      r.x = fmaxf(acc[nb][0] * g.x + bb.x + fv.x, 0.f);
      r.y = fmaxf(acc[nb][1] * g.y + bb.y + fv.y, 0.f);
      r.z = fmaxf(acc[nb][2] * g.z + bb.z + fv.z, 0.f);
      r.w = fmaxf(acc[nb][3] * g.w + bb.w + fv.w, 0.f);
      *(float4*)(out + o) = r;
    }
  }
}

// ---------------------------------------------------------------------------
extern "C" void kernel_launch(void* const* d_in, const int* in_sizes, int n_in,
                              void* d_out, int out_size, void* d_ws, size_t ws_size,
                              hipStream_t stream) {
  const float* F  = (const float*)d_in[0];
  const float* W1 = (const float*)d_in[1];
  const float* W2 = (const float*)d_in[2];
  const float* W3 = (const float*)d_in[3];
  const float* g1 = (const float*)d_in[4];
  const float* b1 = (const float*)d_in[5];
  const float* g2 = (const float*)d_in[6];
  const float* b2 = (const float*)d_in[7];
  const float* g3 = (const float*)d_in[8];
  const float* b3 = (const float*)d_in[9];
  const int*   NB = (const int*)d_in[10];
  float* out = (float*)d_out;

  char* ws = (char*)d_ws;
  short* W1T = (short*)(ws);                                   // 32768 B
  short* W2T = (short*)(ws + 32768);                           // 221184 B
  short* W3T = (short*)(ws + 32768 + 221184);                  // 32768 B
  short* h1  = (short*)(ws + 32768 + 221184 + 32768);          // (N+1)*64*2 = 12800128 B
  short* h2  = (short*)(ws + 32768 + 221184 + 32768 + 12800128); // N*64*2 B

  k_prep<<<dim3(561), dim3(256), 0, stream>>>(W1, W2, W3, W1T, W2T, W3T, h1);
  k_conv1<<<dim3((N_SITES + 63) / 64), dim3(256), 0, stream>>>(F, W1T, g1, b1, h1);
  k_conv2<<<dim3((N_SITES + 127) / 128), dim3(128), 0, stream>>>(h1, W2T, g2, b2, NB, h2);
  k_conv3<<<dim3((N_SITES + 63) / 64), dim3(256), 0, stream>>>(h2, W3T, g3, b3, F, out);
}